// Round 10
// baseline (709.438 us; speedup 1.0000x reference)
//
#include <hip/hip_runtime.h>
#include <hip/hip_bf16.h>
#include <math.h>

// BinaryTreeLSTM — round 10: barrier-free LDS-free register GEMM.
// Fragments (lane = row l&15, k-slice (l>>4)*8) are loaded straight from
// global as dwordx4 — no LDS staging, no __syncthreads in the K-loop.
// Every level: 16x64 output tile per block, 4 waves K-split 4-way,
// LDS reduce (12KB) + in-register LSTM epilogue. GX: same engine, M-stacked.
//
// Packed gate-interleaved column space: e = (j/16)*64 + g*16 + (j%16)
//   (orig W row g*2048+j). Wih_p[4096][1024], Whh_p[4096][2048] bf16,
//   XCD-affine 64-row tiles: tile (e>>6) touched by blocks with b&7==(e>>6)%8.
// GX[4096][4096] fp16: GX[node] = bf16(emb[node]) @ Wih_p^T + bge.
// Hcat: level-k h-slab at row OFF(k)=4096-2^(k+1), 2^k rows x 2048 bf16.
// c compact: level k writes even-node c at row m>>1 (1024 f32); k-1 reads row m.

#define TREE_DEPTH 12

typedef unsigned short u16;
typedef unsigned int u32;
typedef __attribute__((ext_vector_type(8))) short bf16x8;
typedef __attribute__((ext_vector_type(4))) float f32x4;
typedef __attribute__((ext_vector_type(8))) unsigned short u16x8;
typedef __attribute__((ext_vector_type(2))) unsigned int u32x2;

__device__ __forceinline__ u16 f2bf(float f) {
    __hip_bfloat16 h = __float2bfloat16(f);
    return *reinterpret_cast<u16*>(&h);
}
__device__ __forceinline__ u16 f2h(float f) {
    _Float16 h = (_Float16)f;
    return *reinterpret_cast<u16*>(&h);
}
__device__ __forceinline__ float h2f(u16 u) {
    _Float16 h;
    *reinterpret_cast<u16*>(&h) = u;
    return (float)h;
}

// ---------------------------------------------------------------- converts
__global__ void bias_e_kernel(const float* __restrict__ b_ih,
                              const float* __restrict__ b_hh,
                              float* __restrict__ bge) {
    int e = blockIdx.x * blockDim.x + threadIdx.x;   // 0..4095 packed order
    int g = (e >> 4) & 3;
    int j = (e >> 6) * 16 + (e & 15);
    int r = g * 2048 + j;
    bge[e] = b_ih[r] + b_hh[r];
}

// Pack W_ih -> Wih_p[4096][1024], W_hh -> Whh_p[4096][2048]; gate-interleaved
// rows; 64-row tile (e>>6) written by blocks with b&7 == (e>>6)%8.
__global__ void pack_w(const float* __restrict__ Wih,
                       const float* __restrict__ Whh,
                       u16* __restrict__ Wih_p, u16* __restrict__ Whh_p) {
    const int b = blockIdx.x;          // 0..4095
    const int seg = blockIdx.y;        // 0: ih, 1/2: hh halves
    const int x = b & 7, t = b >> 3;   // t in [0,512)
    const int e = (x + 8 * (t >> 6)) * 64 + (t & 63);   // (e>>6)%8 == x
    const int g = (e >> 4) & 3;
    const int j = (e >> 6) * 16 + (e & 15);
    const int wr = g * 2048 + j;
    const int col = threadIdx.x * 4;   // 0..1020
    f32x4 v;
    u16* dst;
    if (seg == 0) {
        v = __builtin_nontemporal_load(
            (const f32x4*)(Wih + (size_t)wr * 1024 + col));
        dst = Wih_p + (size_t)e * 1024 + col;
    } else {
        v = __builtin_nontemporal_load(
            (const f32x4*)(Whh + (size_t)wr * 2048 + (seg - 1) * 1024 + col));
        dst = Whh_p + (size_t)e * 2048 + (seg - 1) * 1024 + col;
    }
    u32x2 p;
    p[0] = (u32)f2bf(v[0]) | ((u32)f2bf(v[1]) << 16);
    p[1] = (u32)f2bf(v[2]) | ((u32)f2bf(v[3]) << 16);
    *reinterpret_cast<u32x2*>(dst) = p;
}

__global__ void conv_emb(const float* __restrict__ emb, u16* __restrict__ xb) {
    size_t idx = ((size_t)blockIdx.x * 256 + threadIdx.x) * 4;  // over 4095*1024
    f32x4 v = __builtin_nontemporal_load((const f32x4*)(emb + idx));
    u32x2 p;
    p[0] = (u32)f2bf(v[0]) | ((u32)f2bf(v[1]) << 16);
    p[1] = (u32)f2bf(v[2]) | ((u32)f2bf(v[3]) << 16);
    *reinterpret_cast<u32x2*>(xb + idx) = p;
}

// ---------------------------------------------------------------- GX GEMM
// GX[m][e] fp16 = xb[m] @ Wih_p[e] + bge[e]. M=N=4096, K=1024.
// Block: 64 rows (4 waves M-stacked) x 64 cols; full K per wave; no LDS.
__global__ __launch_bounds__(256) void gemm_gx_reg(
    const u16* __restrict__ xb, const u16* __restrict__ Wp,
    const float* __restrict__ bge, u16* __restrict__ GX)
{
    const int gx_ = gridDim.x;   // 64
    int b = blockIdx.x + gx_ * blockIdx.y;
    const int x = b & 7, t = b >> 3;
    const int ct = (t & 7) * 8 + x;    // 0..63, ct%8 == XCD
    const int mt = t >> 3;             // 0..63
    const int m0 = mt * 64, c0 = ct * 64;

    const int lane = threadIdx.x & 63;
    const int w = threadIdx.x >> 6;
    const int fl = lane & 15;
    const int kh = (lane >> 4) * 8;

    const u16* pA = xb + (size_t)(m0 + w * 16 + fl) * 1024 + kh;
    const u16* pW = Wp + (size_t)(c0 + fl) * 1024 + kh;

    f32x4 acc[4];
    #pragma unroll
    for (int f = 0; f < 4; ++f) acc[f] = f32x4{0.f, 0.f, 0.f, 0.f};

    #pragma unroll 4
    for (int s = 0; s < 32; ++s) {
        bf16x8 a = *reinterpret_cast<const bf16x8*>(pA);
        #pragma unroll
        for (int f = 0; f < 4; ++f) {
            bf16x8 bb = *reinterpret_cast<const bf16x8*>(pW + (size_t)f * 16 * 1024);
            acc[f] = __builtin_amdgcn_mfma_f32_16x16x32_bf16(a, bb, acc[f], 0, 0, 0);
        }
        pA += 32; pW += 32;
    }

    #pragma unroll
    for (int f = 0; f < 4; ++f) {
        const int c = c0 + f * 16 + fl;
        const float bv = bge[c];
        #pragma unroll
        for (int r = 0; r < 4; ++r) {
            const int m = m0 + w * 16 + (lane >> 4) * 4 + r;
            __builtin_nontemporal_store(f2h(acc[f][r] + bv),
                                        GX + (size_t)m * 4096 + c);
        }
    }
}

// ---------------------------------------------------------------- level 11 act
// gates = GX rows 2047..4094 (h=c=0). h -> Hcat L10 slab, c compact.
__global__ void act_top(const u16* __restrict__ GX, u16* __restrict__ hdst,
                        float* __restrict__ cdst) {
    int idx = blockIdx.x * 256 + threadIdx.x;   // 0..262143
    int m = idx >> 7;            // 0..2047
    int jo = (idx & 127) * 8;    // 0..1016
    const u16* row = GX + (size_t)(2047 + m) * 4096;
    const int eb = (jo >> 4) * 64 + (jo & 8);
    u16x8 gi = __builtin_nontemporal_load((const u16x8*)(row + eb));
    u16x8 gg = __builtin_nontemporal_load((const u16x8*)(row + eb + 32));
    u16x8 go = __builtin_nontemporal_load((const u16x8*)(row + eb + 48));
    u16x8 hp;
    float cn[8];
    #pragma unroll
    for (int q = 0; q < 8; ++q) {
        const float i_ = h2f(gi[q]), g_ = h2f(gg[q]), o_ = h2f(go[q]);
        const float si = 1.0f / (1.0f + expf(-i_));
        const float so = 1.0f / (1.0f + expf(-o_));
        cn[q] = si * tanhf(g_);
        hp[q] = f2bf(so * tanhf(cn[q]));
    }
    *reinterpret_cast<u16x8*>(hdst + (size_t)(m >> 1) * 2048 +
                              (m & 1) * 1024 + jo) = hp;
    if (!(m & 1)) {
        f32x4 c0v = {cn[0], cn[1], cn[2], cn[3]};
        f32x4 c1v = {cn[4], cn[5], cn[6], cn[7]};
        float* cb = cdst + (size_t)(m >> 1) * 1024 + jo;
        __builtin_nontemporal_store(c0v, (f32x4*)cb);
        __builtin_nontemporal_store(c1v, (f32x4*)(cb + 4));
    }
}

// ---------------------------------------------------------------- fused level
// gates = A(h_cat) @ Whh_p^T + GX[node]; K=2048 split over the 4 waves.
// Block: 16 rows x 64 cols; barrier-free reg-GEMM; LDS only for reduce.
__global__ __launch_bounds__(256) void fused_level_reg(
    const u16* __restrict__ A,       // n x 2048 (Hcat slab)
    const u16* __restrict__ Wp,      // Whh_p 4096 x 2048
    const u16* __restrict__ GXl,     // GX + (n-1)*4096 (fp16)
    const float* __restrict__ cprev, // compact c
    u16* __restrict__ hnext,         // Hcat next slab base (or null)
    float* __restrict__ cnext,       // compact c out
    float* __restrict__ outp,        // null unless n==1
    int n)
{
    __shared__ f32x4 red[3][4][64];  // 12 KB

    const int gx_ = gridDim.x;
    int b = blockIdx.x + gx_ * blockIdx.y;
    const int x = b & 7, t = b >> 3;
    const int ct = (t & 7) * 8 + x;    // 0..63, ct%8 == XCD
    const int mt = t >> 3;
    const int m0 = mt * 16;
    const int c0 = ct * 64;

    const int lane = threadIdx.x & 63;
    const int kq = threadIdx.x >> 6;   // K-quarter 0..3
    const int fl = lane & 15;
    const int kh = (lane >> 4) * 8;

    int arow = m0 + fl;
    if (arow >= n) arow = n - 1;
    const u16* pA = A + (size_t)arow * 2048 + kq * 512 + kh;
    const u16* pW = Wp + (size_t)(c0 + fl) * 2048 + kq * 512 + kh;

    f32x4 acc[4];
    #pragma unroll
    for (int f = 0; f < 4; ++f) acc[f] = f32x4{0.f, 0.f, 0.f, 0.f};

    #pragma unroll 4
    for (int s = 0; s < 16; ++s) {
        bf16x8 a = *reinterpret_cast<const bf16x8*>(pA);
        #pragma unroll
        for (int f = 0; f < 4; ++f) {
            bf16x8 bb = *reinterpret_cast<const bf16x8*>(pW + (size_t)f * 16 * 2048);
            acc[f] = __builtin_amdgcn_mfma_f32_16x16x32_bf16(a, bb, acc[f], 0, 0, 0);
        }
        pA += 32; pW += 32;
    }

    if (kq > 0) {
        #pragma unroll
        for (int f = 0; f < 4; ++f) red[kq - 1][f][lane] = acc[f];
    }
    __syncthreads();
    if (kq != 0) return;

    #pragma unroll
    for (int q = 0; q < 3; ++q)
        #pragma unroll
        for (int f = 0; f < 4; ++f) {
            f32x4 v = red[q][f][lane];
            acc[f][0] += v[0]; acc[f][1] += v[1];
            acc[f][2] += v[2]; acc[f][3] += v[3];
        }

    // in-register LSTM cell epilogue
    const int j = ct * 16 + fl;        // true output column
    #pragma unroll
    for (int r = 0; r < 4; ++r) {
        const int m = m0 + (lane >> 4) * 4 + r;
        if (m >= n) continue;
        const u16* gx = GXl + (size_t)m * 4096 + c0 + fl;
        const float i_ = acc[0][r] + h2f(__builtin_nontemporal_load(gx));
        const float f_ = acc[1][r] + h2f(__builtin_nontemporal_load(gx + 16));
        const float g_ = acc[2][r] + h2f(__builtin_nontemporal_load(gx + 32));
        const float o_ = acc[3][r] + h2f(__builtin_nontemporal_load(gx + 48));
        const float cc = __builtin_nontemporal_load(cprev + (size_t)m * 1024 + j);
        const float si = 1.0f / (1.0f + expf(-i_));
        const float sf = 1.0f / (1.0f + expf(-f_));
        const float so = 1.0f / (1.0f + expf(-o_));
        const float cn = sf * cc + si * tanhf(g_);
        const float hn = so * tanhf(cn);
        if (hnext)
            hnext[(size_t)(m >> 1) * 2048 + (m & 1) * 1024 + j] = f2bf(hn);
        if (!(m & 1))
            __builtin_nontemporal_store(cn, cnext + (size_t)(m >> 1) * 1024 + j);
        if (outp) { outp[j] = hn; outp[1024 + j] = cn; }
    }
}

// ---------------------------------------------------------------- launcher
extern "C" void kernel_launch(void* const* d_in, const int* in_sizes, int n_in,
                              void* d_out, int out_size, void* d_ws, size_t ws_size,
                              hipStream_t stream) {
    const float* emb  = (const float*)d_in[0];
    const float* W_ih = (const float*)d_in[1];
    const float* W_hh = (const float*)d_in[2];
    const float* b_ih = (const float*)d_in[3];
    const float* b_hh = (const float*)d_in[4];
    float* out = (float*)d_out;

    char* p = (char*)d_ws;
    float* bge  = (float*)p;  p += 16384;
    u16* Wih_p  = (u16*)p;    p += (size_t)4096 * 1024 * 2;   //  8.4 MB
    u16* Whh_p  = (u16*)p;    p += (size_t)4096 * 2048 * 2;   // 16.8 MB
    u16* xb     = (u16*)p;    p += (size_t)4096 * 1024 * 2;   //  8.4 MB
    u16* GX     = (u16*)p;    p += (size_t)4096 * 4096 * 2;   // 33.6 MB
    u16* Hcat   = (u16*)p;    p += (size_t)4096 * 2048 * 2;   // 16.8 MB
    float* cbA  = (float*)p;  p += (size_t)1024 * 1024 * 4;   //  4.2 MB
    float* cbB  = (float*)p;  p += (size_t)1024 * 1024 * 4;   //  4.2 MB

    bias_e_kernel<<<16, 256, 0, stream>>>(b_ih, b_hh, bge);
    pack_w<<<dim3(4096, 3), 256, 0, stream>>>(W_ih, W_hh, Wih_p, Whh_p);
    conv_emb<<<4095, 256, 0, stream>>>(emb, xb);

    // GX for all nodes: 4096 blocks, no LDS, no barriers.
    gemm_gx_reg<<<dim3(64, 64), 256, 0, stream>>>(xb, Wih_p, bge, GX);

    #define OFF(k) (4096 - (2 << (k)))

    // level 11 is pure act from GX.
    act_top<<<1024, 256, 0, stream>>>(GX, Hcat + (size_t)OFF(10) * 2048, cbA);

    const float* cprev = cbA;
    float* cbufs[2] = {cbB, cbA};
    int t = 0;
    for (int k = TREE_DEPTH - 2; k >= 0; --k) {
        const int n = 1 << k;
        const u16* A = Hcat + (size_t)OFF(k) * 2048;
        const u16* GXl = GX + (size_t)(n - 1) * 4096;
        u16* hnext = (k > 0) ? (Hcat + (size_t)OFF(k - 1) * 2048) : nullptr;
        float* cnext = cbufs[t];
        float* outp = (k == 0) ? out : nullptr;

        const int gx = (n >= 16) ? n / 16 : 1;
        fused_level_reg<<<dim3(gx, 64), 256, 0, stream>>>(
            A, Whh_p, GXl, cprev, hnext, cnext, outp, n);

        cprev = cnext; t ^= 1;
    }
}

// Round 11
// 300.391 us; speedup vs baseline: 2.3617x; 2.3617x over previous
//
#include <hip/hip_runtime.h>
#include <hip/hip_bf16.h>
#include <math.h>

// BinaryTreeLSTM — round 11: GX hoist + fused levels with r5-proven
// 128-row 2-phase LDS GEMM geometry and in-block K-split (KG) so every
// big level runs 256 blocks x 8 waves (2 waves/SIMD chip-wide).
//
// Packed gate-interleaved column space: e = (j/16)*64 + g*16 + (j%16)
//   (orig W row g*2048+j). Wih_p[4096][1024], Whh_p[4096][2048] bf16,
//   XCD-affine 128-row tiles: tile (e>>7) written by blocks with b&7==(e>>7)%8.
// GX[4096][4096] fp16: GX[node] = bf16(emb[node]) @ Wih_p^T + bge.
// Hcat: level-k h-slab at row OFF(k)=4096-2^(k+1), 2^k rows x 2048 bf16.
// c compact: level k writes even-node c at row m>>1 (1024 f32); k-1 reads row m.

#define TREE_DEPTH 12

typedef unsigned short u16;
typedef unsigned int u32;
typedef __attribute__((ext_vector_type(8))) short bf16x8;
typedef __attribute__((ext_vector_type(4))) float f32x4;
typedef __attribute__((ext_vector_type(8))) unsigned short u16x8;
typedef __attribute__((ext_vector_type(2))) unsigned int u32x2;

__device__ __forceinline__ void gload16(const void* g, void* l) {
    __builtin_amdgcn_global_load_lds(
        (const __attribute__((address_space(1))) u32*)g,
        (__attribute__((address_space(3))) u32*)l, 16, 0, 0);
}

__device__ __forceinline__ u16 f2bf(float f) {
    __hip_bfloat16 h = __float2bfloat16(f);
    return *reinterpret_cast<u16*>(&h);
}
__device__ __forceinline__ u16 f2h(float f) {
    _Float16 h = (_Float16)f;
    return *reinterpret_cast<u16*>(&h);
}
__device__ __forceinline__ float h2f(u16 u) {
    _Float16 h;
    *reinterpret_cast<u16*>(&h) = u;
    return (float)h;
}

// ---------------------------------------------------------------- converts
__global__ void bias_e_kernel(const float* __restrict__ b_ih,
                              const float* __restrict__ b_hh,
                              float* __restrict__ bge) {
    int e = blockIdx.x * blockDim.x + threadIdx.x;   // 0..4095 packed order
    int g = (e >> 4) & 3;
    int j = (e >> 6) * 16 + (e & 15);
    int r = g * 2048 + j;
    bge[e] = b_ih[r] + b_hh[r];
}

// Pack W_ih -> Wih_p[4096][1024], W_hh -> Whh_p[4096][2048]; gate-interleaved
// rows; 128-row tile (e>>7) written by blocks with b&7 == (e>>7)%8.
__global__ void pack_w(const float* __restrict__ Wih,
                       const float* __restrict__ Whh,
                       u16* __restrict__ Wih_p, u16* __restrict__ Whh_p) {
    const int b = blockIdx.x;          // 0..4095
    const int seg = blockIdx.y;        // 0: ih, 1/2: hh halves
    const int x = b & 7, t = b >> 3;   // t in [0,512)
    const int e = ((t & 3) * 8 + x) * 128 + (t >> 2);  // (e>>7)%8 == x
    const int g = (e >> 4) & 3;
    const int j = (e >> 6) * 16 + (e & 15);
    const int wr = g * 2048 + j;
    const int col = threadIdx.x * 4;   // 0..1020
    f32x4 v;
    u16* dst;
    if (seg == 0) {
        v = __builtin_nontemporal_load(
            (const f32x4*)(Wih + (size_t)wr * 1024 + col));
        dst = Wih_p + (size_t)e * 1024 + col;
    } else {
        v = __builtin_nontemporal_load(
            (const f32x4*)(Whh + (size_t)wr * 2048 + (seg - 1) * 1024 + col));
        dst = Whh_p + (size_t)e * 2048 + (seg - 1) * 1024 + col;
    }
    u32x2 p;
    p[0] = (u32)f2bf(v[0]) | ((u32)f2bf(v[1]) << 16);
    p[1] = (u32)f2bf(v[2]) | ((u32)f2bf(v[3]) << 16);
    *reinterpret_cast<u32x2*>(dst) = p;
}

__global__ void conv_emb(const float* __restrict__ emb, u16* __restrict__ xb) {
    size_t idx = ((size_t)blockIdx.x * 256 + threadIdx.x) * 4;  // over 4095*1024
    f32x4 v = __builtin_nontemporal_load((const f32x4*)(emb + idx));
    u32x2 p;
    p[0] = (u32)f2bf(v[0]) | ((u32)f2bf(v[1]) << 16);
    p[1] = (u32)f2bf(v[2]) | ((u32)f2bf(v[3]) << 16);
    *reinterpret_cast<u32x2*>(xb + idx) = p;
}

// ---------------------------------------------------------------- GX GEMM
// GX[m][e] fp16 = xb[m] @ Wih_p[e] + bge[e].  M=4096, N=4096, K=1024.
// 128x128 tile, 4 waves (64x64), BK=32, single-buffer 2-phase (r9-proven).
__global__ __launch_bounds__(256) void gemm_gx(
    const u16* __restrict__ xb, const u16* __restrict__ Wp,
    const float* __restrict__ bge, u16* __restrict__ GX)
{
    __shared__ u16 smem[(128 + 128) * 32];   // 16 KB

    const int gx_ = gridDim.x;   // 32
    int b = blockIdx.x + gx_ * blockIdx.y;
    const int x = b & 7, t = b >> 3;
    const int ct = (t & 3) * 8 + x;
    const int mt = t >> 2;
    const int m0 = mt * 128, c0 = ct * 128;

    const int tid = threadIdx.x, lane = tid & 63, w = tid >> 6;
    const int wr = (w >> 1) * 64, wc = (w & 1) * 64;

    f32x4 acc[4][4];
    #pragma unroll
    for (int i = 0; i < 4; ++i)
        #pragma unroll
        for (int j = 0; j < 4; ++j)
            acc[i][j] = f32x4{0.f, 0.f, 0.f, 0.f};

    const u16* gp[4];
    u16* dl[4];
    #pragma unroll
    for (int i = 0; i < 4; ++i) {
        const int s = tid + i * 256;
        const int row = s >> 2, kof = (s & 3) * 8;
        gp[i] = (row < 128) ? xb + (size_t)(m0 + row) * 1024 + kof
                            : Wp + (size_t)(c0 + row - 128) * 1024 + kof;
        dl[i] = smem + s * 8;
    }

    const int fl = lane & 15, kb = (lane >> 4) * 8;
    for (int k0 = 0; k0 < 1024; k0 += 32) {
        #pragma unroll
        for (int i = 0; i < 4; ++i) { gload16(gp[i], dl[i]); gp[i] += 32; }
        __syncthreads();
        bf16x8 a_[4], b_[4];
        #pragma unroll
        for (int i = 0; i < 4; ++i)
            a_[i] = *reinterpret_cast<const bf16x8*>(
                &smem[(wr + i * 16 + fl) * 32 + kb]);
        #pragma unroll
        for (int j = 0; j < 4; ++j)
            b_[j] = *reinterpret_cast<const bf16x8*>(
                &smem[(128 + wc + j * 16 + fl) * 32 + kb]);
        #pragma unroll
        for (int i = 0; i < 4; ++i)
            #pragma unroll
            for (int j = 0; j < 4; ++j)
                acc[i][j] = __builtin_amdgcn_mfma_f32_16x16x32_bf16(
                    a_[i], b_[j], acc[i][j], 0, 0, 0);
        __syncthreads();
    }

    const int rg = (lane >> 4) * 4;
    #pragma unroll
    for (int i = 0; i < 4; ++i)
        #pragma unroll
        for (int j = 0; j < 4; ++j) {
            const int c = c0 + wc + j * 16 + fl;
            const float bv = bge[c];
            #pragma unroll
            for (int r = 0; r < 4; ++r) {
                const int m = m0 + wr + i * 16 + rg + r;
                __builtin_nontemporal_store(
                    f2h(acc[i][j][r] + bv), GX + (size_t)m * 4096 + c);
            }
        }
}

// ---------------------------------------------------------------- level 11 act
__global__ void act_top(const u16* __restrict__ GX, u16* __restrict__ hdst,
                        float* __restrict__ cdst) {
    int idx = blockIdx.x * 256 + threadIdx.x;   // 0..262143
    int m = idx >> 7;            // 0..2047
    int jo = (idx & 127) * 8;    // 0..1016
    const u16* row = GX + (size_t)(2047 + m) * 4096;
    const int eb = (jo >> 4) * 64 + (jo & 8);
    u16x8 gi = __builtin_nontemporal_load((const u16x8*)(row + eb));
    u16x8 gg = __builtin_nontemporal_load((const u16x8*)(row + eb + 32));
    u16x8 go = __builtin_nontemporal_load((const u16x8*)(row + eb + 48));
    u16x8 hp;
    float cn[8];
    #pragma unroll
    for (int q = 0; q < 8; ++q) {
        const float i_ = h2f(gi[q]), g_ = h2f(gg[q]), o_ = h2f(go[q]);
        const float si = 1.0f / (1.0f + expf(-i_));
        const float so = 1.0f / (1.0f + expf(-o_));
        cn[q] = si * tanhf(g_);
        hp[q] = f2bf(so * tanhf(cn[q]));
    }
    *reinterpret_cast<u16x8*>(hdst + (size_t)(m >> 1) * 2048 +
                              (m & 1) * 1024 + jo) = hp;
    if (!(m & 1)) {
        f32x4 c0v = {cn[0], cn[1], cn[2], cn[3]};
        f32x4 c1v = {cn[4], cn[5], cn[6], cn[7]};
        float* cb = cdst + (size_t)(m >> 1) * 1024 + jo;
        __builtin_nontemporal_store(c0v, (f32x4*)cb);
        __builtin_nontemporal_store(c1v, (f32x4*)(cb + 4));
    }
}

// ---------------------------------------------------------------- fused level
// gates = A(h_cat) @ Whh_p^T + GX[node]; K=2048 split KG ways in-block.
template <int MI, int MW, int NW, int KG>
__global__ __launch_bounds__(MW* NW* KG * 64) void fused_level(
    const u16* __restrict__ A,       // n x 2048 (Hcat slab)
    const u16* __restrict__ Wp,      // Whh_p 4096 x 2048
    const u16* __restrict__ GXl,     // GX + (n-1)*4096 (fp16)
    const float* __restrict__ cprev, // compact c
    u16* __restrict__ hnext,         // Hcat next slab base (or null)
    float* __restrict__ cnext,       // compact c out
    float* __restrict__ outp,        // null unless n==1
    int n)
{
    constexpr int BM = MI * 16 * MW;
    constexpr int BN = NW * 64;
    constexpr int S = MW * NW;
    constexpr int NFR = MI * 4;
    constexpr int RC = NFR > 8 ? 8 : NFR;
    constexpr int NP = NFR / RC;
    constexpr int ROWS = BM + BN;
    constexpr int SLOTS = ROWS * 4;
    constexpr int GT = S * 64;
    constexpr int NL = SLOTS / GT;
    static_assert(SLOTS % GT == 0, "slot mapping must be exact");
    constexpr int STG = KG * ROWS * 64;
    constexpr int REDB = (KG > 1) ? (KG - 1) * S * RC * 64 * 16 : 0;
    constexpr int SMEM = STG > REDB ? STG : REDB;
    __shared__ __align__(16) char smem[SMEM];

    const int gx_ = gridDim.x;
    int b = blockIdx.x + gx_ * blockIdx.y;
    const int x = b & 7;
    int t = b >> 3;
    int ct, mt;
    if constexpr (NW == 2) {
        ct = (t & 3) * 8 + x; mt = t >> 2;
    } else {
        const int lo = t & 1; t >>= 1;
        ct = ((t & 3) * 8 + x) * 2 + lo; mt = t >> 2;
    }
    const int m0 = mt * BM;
    const int c0 = ct * BN;

    const int tid = threadIdx.x;
    const int lane = tid & 63;
    const int w = tid >> 6;
    const int kg = w / S;
    const int slot = w % S;
    const int wm = slot / NW;
    const int wn = slot % NW;

    const int Kc = 2048 / KG;
    const int kbeg = kg * Kc;

    u16* buf = (u16*)smem + (size_t)kg * ROWS * 32;

    const int gtid = slot * 64 + lane;
    const u16* gp[NL];
    u16* dl[NL];
    #pragma unroll
    for (int i = 0; i < NL; ++i) {
        const int s = gtid + i * GT;
        const int row = s >> 2;
        const int kof = (s & 3) * 8;
        if (row < BM) {
            int ar = m0 + row;
            if (ar >= n) ar = n - 1;
            gp[i] = A + (size_t)ar * 2048 + kbeg + kof;
        } else {
            gp[i] = Wp + (size_t)(c0 + row - BM) * 2048 + kbeg + kof;
        }
        dl[i] = buf + s * 8;
    }

    f32x4 acc[MI][4];
    #pragma unroll
    for (int mi = 0; mi < MI; ++mi)
        #pragma unroll
        for (int f = 0; f < 4; ++f)
            acc[mi][f] = f32x4{0.f, 0.f, 0.f, 0.f};

    const int fl = lane & 15;
    const int kb = (lane >> 4) * 8;
    const int ar0 = wm * MI * 16;
    const int bc0 = BM;

    for (int k0 = 0; k0 < Kc; k0 += 32) {
        #pragma unroll
        for (int i = 0; i < NL; ++i) { gload16(gp[i], dl[i]); gp[i] += 32; }
        __syncthreads();
        bf16x8 a_[MI], b_[4];
        #pragma unroll
        for (int mi = 0; mi < MI; ++mi)
            a_[mi] = *reinterpret_cast<const bf16x8*>(
                buf + (ar0 + mi * 16 + fl) * 32 + kb);
        #pragma unroll
        for (int f = 0; f < 4; ++f)
            b_[f] = *reinterpret_cast<const bf16x8*>(
                buf + (bc0 + wn * 64 + f * 16 + fl) * 32 + kb);
        #pragma unroll
        for (int mi = 0; mi < MI; ++mi)
            #pragma unroll
            for (int f = 0; f < 4; ++f)
                acc[mi][f] = __builtin_amdgcn_mfma_f32_16x16x32_bf16(
                    a_[mi], b_[f], acc[mi][f], 0, 0, 0);
        __syncthreads();
    }

    // cross-K-group reduction (reuse smem)
    if constexpr (KG > 1) {
        f32x4* red = reinterpret_cast<f32x4*>(smem);
        #pragma unroll
        for (int pass = 0; pass < NP; ++pass) {
            if (kg > 0) {
                #pragma unroll
                for (int f = 0; f < RC; ++f) {
                    const int fr = pass * RC + f;
                    red[(((kg - 1) * S + slot) * RC + f) * 64 + lane] =
                        acc[fr >> 2][fr & 3];
                }
            }
            __syncthreads();
            if (kg == 0) {
                #pragma unroll
                for (int q = 1; q < KG; ++q)
                    #pragma unroll
                    for (int f = 0; f < RC; ++f) {
                        const int fr = pass * RC + f;
                        f32x4 v = red[(((q - 1) * S + slot) * RC + f) * 64 + lane];
                        acc[fr >> 2][fr & 3][0] += v[0];
                        acc[fr >> 2][fr & 3][1] += v[1];
                        acc[fr >> 2][fr & 3][2] += v[2];
                        acc[fr >> 2][fr & 3][3] += v[3];
                    }
            }
            __syncthreads();
        }
    }

    // LSTM cell epilogue (kg == 0 waves)
    if (kg != 0) return;
    const int j = ((c0 + wn * 64) >> 6) * 16 + fl;   // true output column
    #pragma unroll
    for (int mi = 0; mi < MI; ++mi) {
        #pragma unroll
        for (int r = 0; r < 4; ++r) {
            const int m = m0 + wm * MI * 16 + mi * 16 + (lane >> 4) * 4 + r;
            if (m >= n) continue;
            const u16* gx = GXl + (size_t)m * 4096 + c0 + wn * 64 + fl;
            const float i_ = acc[mi][0][r] + h2f(__builtin_nontemporal_load(gx));
            const float f_ = acc[mi][1][r] + h2f(__builtin_nontemporal_load(gx + 16));
            const float g_ = acc[mi][2][r] + h2f(__builtin_nontemporal_load(gx + 32));
            const float o_ = acc[mi][3][r] + h2f(__builtin_nontemporal_load(gx + 48));
            const float cc = __builtin_nontemporal_load(cprev + (size_t)m * 1024 + j);
            const float si = 1.0f / (1.0f + expf(-i_));
            const float sf = 1.0f / (1.0f + expf(-f_));
            const float so = 1.0f / (1.0f + expf(-o_));
            const float cn = sf * cc + si * tanhf(g_);
            const float hn = so * tanhf(cn);
            if (hnext)
                hnext[(size_t)(m >> 1) * 2048 + (m & 1) * 1024 + j] = f2bf(hn);
            if (!(m & 1))
                __builtin_nontemporal_store(cn, cnext + (size_t)(m >> 1) * 1024 + j);
            if (outp) { outp[j] = hn; outp[1024 + j] = cn; }
        }
    }
}

// ---------------------------------------------------------------- launcher
extern "C" void kernel_launch(void* const* d_in, const int* in_sizes, int n_in,
                              void* d_out, int out_size, void* d_ws, size_t ws_size,
                              hipStream_t stream) {
    const float* emb  = (const float*)d_in[0];
    const float* W_ih = (const float*)d_in[1];
    const float* W_hh = (const float*)d_in[2];
    const float* b_ih = (const float*)d_in[3];
    const float* b_hh = (const float*)d_in[4];
    float* out = (float*)d_out;

    char* p = (char*)d_ws;
    float* bge  = (float*)p;  p += 16384;
    u16* Wih_p  = (u16*)p;    p += (size_t)4096 * 1024 * 2;   //  8.4 MB
    u16* Whh_p  = (u16*)p;    p += (size_t)4096 * 2048 * 2;   // 16.8 MB
    u16* xb     = (u16*)p;    p += (size_t)4096 * 1024 * 2;   //  8.4 MB
    u16* GX     = (u16*)p;    p += (size_t)4096 * 4096 * 2;   // 33.6 MB
    u16* Hcat   = (u16*)p;    p += (size_t)4096 * 2048 * 2;   // 16.8 MB
    float* cbA  = (float*)p;  p += (size_t)1024 * 1024 * 4;   //  4.2 MB
    float* cbB  = (float*)p;  p += (size_t)1024 * 1024 * 4;   //  4.2 MB

    bias_e_kernel<<<16, 256, 0, stream>>>(b_ih, b_hh, bge);
    pack_w<<<dim3(4096, 3), 256, 0, stream>>>(W_ih, W_hh, Wih_p, Whh_p);
    conv_emb<<<4095, 256, 0, stream>>>(emb, xb);

    // GX for all nodes: 1024 blocks of 128x128 (4/CU).
    gemm_gx<<<dim3(32, 32), 256, 0, stream>>>(xb, Wih_p, bge, GX);

    #define OFF(k) (4096 - (2 << (k)))

    // level 11 is pure act from GX.
    act_top<<<1024, 256, 0, stream>>>(GX, Hcat + (size_t)OFF(10) * 2048, cbA);

    const float* cprev = cbA;
    float* cbufs[2] = {cbB, cbA};
    int t = 0;
    for (int k = TREE_DEPTH - 2; k >= 0; --k) {
        const int n = 1 << k;
        const u16* A = Hcat + (size_t)OFF(k) * 2048;
        const u16* GXl = GX + (size_t)(n - 1) * 4096;
        u16* hnext = (k > 0) ? (Hcat + (size_t)OFF(k - 1) * 2048) : nullptr;
        float* cnext = cbufs[t];
        float* outp = (k == 0) ? out : nullptr;

        if (k == 10) {
            // BM=128, BN=128, 8 waves (4 compute x KG=2): 256 blocks.
            fused_level<4, 2, 2, 2><<<dim3(8, 32), 512, 0, stream>>>(
                A, Whh_p, GXl, cprev, hnext, cnext, outp, n);
        } else if (k == 9) {
            // BM=64, BN=128, 8 waves (2 x KG=4): 256 blocks.
            fused_level<4, 1, 2, 4><<<dim3(8, 32), 512, 0, stream>>>(
                A, Whh_p, GXl, cprev, hnext, cnext, outp, n);
        } else if (k == 8) {
            // BM=32, BN=128, 8 waves (2 x KG=4): 256 blocks.
            fused_level<2, 1, 2, 4><<<dim3(8, 32), 512, 0, stream>>>(
                A, Whh_p, GXl, cprev, hnext, cnext, outp, n);
        } else {
            // BM=16, BN=64, 8 waves (1 x KG=8): up to 512 blocks.
            const int gx = (n >= 16) ? n / 16 : 1;
            fused_level<1, 1, 1, 8><<<dim3(gx, 64), 512, 0, stream>>>(
                A, Whh_p, GXl, cprev, hnext, cnext, outp, n);
        }
        cprev = cnext; t ^= 1;
    }
}